// Round 5
// baseline (20447.417 us; speedup 1.0000x reference)
//
#include <hip/hip_runtime.h>

#define FF 512
#define HH 1024
#define LL 128
#define BB 128
#define PP 1024

typedef short short8 __attribute__((ext_vector_type(8)));
typedef float floatx4 __attribute__((ext_vector_type(4)));
typedef unsigned short ushort_t;

__device__ __forceinline__ float sigm(float x) {
    return 1.0f / (1.0f + __expf(-x));
}
// overflow-safe tanh: exp(-2|x|) underflows to 0 for large |x| -> +-1
__device__ __forceinline__ float tanh_fast(float x) {
    float ax = fabsf(x);
    float e = __expf(-2.0f * ax);
    float r = (1.0f - e) / (1.0f + e);
    return copysignf(r, x);
}

__device__ __forceinline__ unsigned short bf16_rtne(float x) {
    unsigned int u = __float_as_uint(x);
    return (unsigned short)((u + 0x7FFFu + ((u >> 16) & 1u)) >> 16);
}
__device__ __forceinline__ void split_bf16(float x, unsigned short& hi, unsigned short& lo) {
    hi = bf16_rtne(x);
    float hf = __uint_as_float(((unsigned int)hi) << 16);
    lo = bf16_rtne(x - hf);
}

__global__ void fillz(float* p, int n) {
    int i = blockIdx.x * blockDim.x + threadIdx.x;
    if (i < n) p[i] = 0.0f;
}

// fp32 [n] -> bf16 hi/lo [n]
__global__ void split_w(const float* __restrict__ W, ushort_t* __restrict__ hi,
                        ushort_t* __restrict__ lo, int n) {
    int i = blockIdx.x * blockDim.x + threadIdx.x;
    if (i < n) {
        unsigned short h, l;
        split_bf16(W[i], h, l);
        hi[i] = h; lo[i] = l;
    }
}

// ---------------------------------------------------------------------------
// 32-block group barrier (blocks sharing one bx f-group). Device-scope
// monotone counter; release fence before arrive, acquire fence after wait.
// Deadlock-safe: grid=256, launch_bounds(256,2) -> >=2 blocks/CU capacity,
// so all blocks are always co-resident.
// ---------------------------------------------------------------------------
__device__ __forceinline__ void group_bar(unsigned int* cnt, unsigned int target) {
    __syncthreads();
    if (threadIdx.x == 0) {
        __threadfence();
        __hip_atomic_fetch_add(cnt, 1u, __ATOMIC_RELEASE, __HIP_MEMORY_SCOPE_AGENT);
        while (__hip_atomic_load(cnt, __ATOMIC_RELAXED, __HIP_MEMORY_SCOPE_AGENT) < target)
            __builtin_amdgcn_s_sleep(2);
    }
    __syncthreads();
    __threadfence();   // acquire: invalidate L1/L2 so peer writes are visible
}

// ---------------------------------------------------------------------------
// One LSTM timestep tile (64 f-rows x 32 cols x 4 gates), bf16-split MFMA:
// g = init + h @ W_hh^T via h_hi*W_hi + h_lo*W_hi + h_hi*W_lo.
// B direct global->fragment (L2-resident, XCD-swizzled), A staged in LDS.
// ---------------------------------------------------------------------------
__device__ __forceinline__ void lstm_tile(
    char* smem, int tid, int bx, int by,
    const float* __restrict__ h_in,
    const ushort_t* __restrict__ hhi, const ushort_t* __restrict__ hlo,
    float* __restrict__ h_out,
    ushort_t* __restrict__ hhi_o, ushort_t* __restrict__ hlo_o,
    float* __restrict__ c_st,
    const ushort_t* __restrict__ Whi, const ushort_t* __restrict__ Wlo,
    const float* __restrict__ initE,
    const int* __restrict__ tokens, const int* __restrict__ lengths, int t)
{
    char* As_hi = smem;                  // 8 KB: 64 rows x 8 slots x 16 B
    char* As_lo = smem + 8192;
    float* Gx = (float*)smem;            // epilogue reuse: [4][64][36] fp32

    const int w = tid >> 6;              // wave index = gate
    const int l = tid & 63;
    const int q = l >> 4;                // k-quad 0..3
    const int fr = l & 15;               // fragment row/col
    const int fbase = bx * 64;
    const int n0 = by * 32;

    const int ar = tid >> 2;
    const int s0 = tid & 3;
    const size_t a_goff = (size_t)(fbase + ar) * HH + s0 * 8;

    const size_t brow0 = ((size_t)(w * HH) + n0 + 0 * 16 + fr) * HH + q * 8;
    const size_t brow1 = ((size_t)(w * HH) + n0 + 1 * 16 + fr) * HH + q * 8;

    floatx4 acc[4][2];
    #pragma unroll
    for (int m = 0; m < 4; ++m)
        #pragma unroll
        for (int n = 0; n < 2; ++n) acc[m][n] = (floatx4)(0.0f);

    int4 pa_h0 = *(const int4*)(hhi + a_goff);
    int4 pa_h1 = *(const int4*)(hhi + a_goff + 32);
    int4 pa_l0 = *(const int4*)(hlo + a_goff);
    int4 pa_l1 = *(const int4*)(hlo + a_goff + 32);

    short8 Bh[2][2][2], Bl[2][2][2];
    #pragma unroll
    for (int kk = 0; kk < 2; ++kk) {
        Bh[0][0][kk] = *(const short8*)(Whi + brow0 + kk * 32);
        Bh[0][1][kk] = *(const short8*)(Whi + brow1 + kk * 32);
        Bl[0][0][kk] = *(const short8*)(Wlo + brow0 + kk * 32);
        Bl[0][1][kk] = *(const short8*)(Wlo + brow1 + kk * 32);
    }

    const int sw0 = (s0 + ar) & 7;
    const int sw1 = ((s0 + 4) + ar) & 7;

    #pragma unroll 2
    for (int kc = 0; kc < 16; ++kc) {
        const int cur = kc & 1, nxt = cur ^ 1;
        __syncthreads();
        ((int4*)As_hi)[ar * 8 + sw0] = pa_h0;
        ((int4*)As_hi)[ar * 8 + sw1] = pa_h1;
        ((int4*)As_lo)[ar * 8 + sw0] = pa_l0;
        ((int4*)As_lo)[ar * 8 + sw1] = pa_l1;
        __syncthreads();

        if (kc < 15) {
            const int k0 = (kc + 1) * 64;
            pa_h0 = *(const int4*)(hhi + a_goff + k0);
            pa_h1 = *(const int4*)(hhi + a_goff + k0 + 32);
            pa_l0 = *(const int4*)(hlo + a_goff + k0);
            pa_l1 = *(const int4*)(hlo + a_goff + k0 + 32);
            #pragma unroll
            for (int kk = 0; kk < 2; ++kk) {
                Bh[nxt][0][kk] = *(const short8*)(Whi + brow0 + k0 + kk * 32);
                Bh[nxt][1][kk] = *(const short8*)(Whi + brow1 + k0 + kk * 32);
                Bl[nxt][0][kk] = *(const short8*)(Wlo + brow0 + k0 + kk * 32);
                Bl[nxt][1][kk] = *(const short8*)(Wlo + brow1 + k0 + kk * 32);
            }
        }

        #pragma unroll
        for (int m = 0; m < 4; ++m) {
            const int r = m * 16 + fr;
            short8 ah0 = *(const short8*)(As_hi + (r * 8 + ((0 * 4 + q + r) & 7)) * 16);
            short8 ah1 = *(const short8*)(As_hi + (r * 8 + ((1 * 4 + q + r) & 7)) * 16);
            short8 al0 = *(const short8*)(As_lo + (r * 8 + ((0 * 4 + q + r) & 7)) * 16);
            short8 al1 = *(const short8*)(As_lo + (r * 8 + ((1 * 4 + q + r) & 7)) * 16);
            #pragma unroll
            for (int n = 0; n < 2; ++n) {
                acc[m][n] = __builtin_amdgcn_mfma_f32_16x16x32_bf16(ah0, Bh[cur][n][0], acc[m][n], 0, 0, 0);
                acc[m][n] = __builtin_amdgcn_mfma_f32_16x16x32_bf16(al0, Bh[cur][n][0], acc[m][n], 0, 0, 0);
                acc[m][n] = __builtin_amdgcn_mfma_f32_16x16x32_bf16(ah0, Bl[cur][n][0], acc[m][n], 0, 0, 0);
                acc[m][n] = __builtin_amdgcn_mfma_f32_16x16x32_bf16(ah1, Bh[cur][n][1], acc[m][n], 0, 0, 0);
                acc[m][n] = __builtin_amdgcn_mfma_f32_16x16x32_bf16(al1, Bh[cur][n][1], acc[m][n], 0, 0, 0);
                acc[m][n] = __builtin_amdgcn_mfma_f32_16x16x32_bf16(ah1, Bl[cur][n][1], acc[m][n], 0, 0, 0);
            }
        }
    }

    // --- gate exchange (C/D: col = fr, row = q*4 + reg); row stride 36 ---
    __syncthreads();
    #pragma unroll
    for (int m = 0; m < 4; ++m)
        #pragma unroll
        for (int n = 0; n < 2; ++n)
            #pragma unroll
            for (int r = 0; r < 4; ++r)
                Gx[(w * 64 + m * 16 + q * 4 + r) * 36 + n * 16 + fr] = acc[m][n][r];
    __syncthreads();

    // --- fused cell update: thread -> (row rr, 8 consecutive cols) ---
    const int rr = tid >> 2;
    const int c0 = (tid & 3) * 8;
    const int f = fbase + rr;
    const int gc = n0 + c0;
    const size_t gidx = (size_t)f * HH + gc;
    const float* ib = tokens ? (initE + (size_t)tokens[f * LL + t] * 4096)
                             : (initE + (size_t)f * 4096);
    const bool upd = lengths ? (t < lengths[f]) : true;

    float4 gv[4][2];
    #pragma unroll
    for (int g = 0; g < 4; ++g) {
        gv[g][0] = *(const float4*)&Gx[(g * 64 + rr) * 36 + c0];
        gv[g][1] = *(const float4*)&Gx[(g * 64 + rr) * 36 + c0 + 4];
        const float4 ibv0 = *(const float4*)(ib + g * 1024 + gc);
        const float4 ibv1 = *(const float4*)(ib + g * 1024 + gc + 4);
        gv[g][0].x += ibv0.x; gv[g][0].y += ibv0.y; gv[g][0].z += ibv0.z; gv[g][0].w += ibv0.w;
        gv[g][1].x += ibv1.x; gv[g][1].y += ibv1.y; gv[g][1].z += ibv1.z; gv[g][1].w += ibv1.w;
    }
    float4 coldv[2] = { *(const float4*)(c_st + gidx), *(const float4*)(c_st + gidx + 4) };
    float4 holdv[2] = { *(const float4*)(h_in + gidx), *(const float4*)(h_in + gidx + 4) };

    float4 cw[2], hw[2];
    int4 hiv, lov;
    #pragma unroll
    for (int hf = 0; hf < 2; ++hf) {
        const float* gi = (const float*)&gv[0][hf];
        const float* gf = (const float*)&gv[1][hf];
        const float* gg = (const float*)&gv[2][hf];
        const float* go = (const float*)&gv[3][hf];
        const float* co = (const float*)&coldv[hf];
        const float* ho = (const float*)&holdv[hf];
        #pragma unroll
        for (int j = 0; j < 4; ++j) {
            float cn = sigm(gf[j]) * co[j] + sigm(gi[j]) * tanh_fast(gg[j]);
            float hn = sigm(go[j]) * tanh_fast(cn);
            float cv = upd ? cn : co[j];
            float hv = upd ? hn : ho[j];
            ((float*)&cw[hf])[j] = cv;
            ((float*)&hw[hf])[j] = hv;
            unsigned short hb, lb;
            split_bf16(hv, hb, lb);
            ((ushort_t*)&hiv)[hf * 4 + j] = hb;
            ((ushort_t*)&lov)[hf * 4 + j] = lb;
        }
    }
    *(float4*)(c_st + gidx) = cw[0];
    *(float4*)(c_st + gidx + 4) = cw[1];
    *(float4*)(h_out + gidx) = hw[0];
    *(float4*)(h_out + gidx + 4) = hw[1];
    *(int4*)(hhi_o + gidx) = hiv;
    *(int4*)(hlo_o + gidx) = lov;
}

// ---------------------------------------------------------------------------
// pooled[b][n] = tanh(max over 4 examples of h@Wmp^T + bmp); group-local
// tile: programs [bx*16,+16) x cols [by*32,+32), fp32 VALU.
// ---------------------------------------------------------------------------
__device__ __forceinline__ void pool_tile(char* smem, int tid, int bx, int by,
    const float* __restrict__ h, const float* __restrict__ Wmp,
    const float* __restrict__ bmp, float* __restrict__ pooled)
{
    float* As = (float*)smem;            // [16][64]
    float* Bs = (float*)(smem + 4096);   // [16][32]
    const int tm = tid & 15;
    const int tn = tid >> 4;
    const int fbase = bx * 64, n0 = by * 32;
    const int ar = tid >> 2;
    const int ak = (tid & 3) * 4;
    const int br = tid >> 3;
    const int bk = (tid & 7) * 2;
    const float* arow = h + (size_t)(fbase + ar) * HH + ak;
    const float* brow = Wmp + (size_t)(n0 + br) * HH + bk;
    float acc[4][2] = {};
    const int tm4 = tm * 4, tn2 = tn * 2;
    for (int k0 = 0; k0 < HH; k0 += 16) {
        __syncthreads();
        float4 av = *(const float4*)(arow + k0);
        float2 bv = *(const float2*)(brow + k0);
        As[(ak + 0) * 64 + ar] = av.x; As[(ak + 1) * 64 + ar] = av.y;
        As[(ak + 2) * 64 + ar] = av.z; As[(ak + 3) * 64 + ar] = av.w;
        Bs[(bk + 0) * 32 + br] = bv.x; Bs[(bk + 1) * 32 + br] = bv.y;
        __syncthreads();
        #pragma unroll
        for (int k = 0; k < 16; ++k) {
            float4 a = *(const float4*)&As[k * 64 + tm4];
            float2 b = *(const float2*)&Bs[k * 32 + tn2];
            acc[0][0] += a.x * b.x; acc[0][1] += a.x * b.y;
            acc[1][0] += a.y * b.x; acc[1][1] += a.y * b.y;
            acc[2][0] += a.z * b.x; acc[2][1] += a.z * b.y;
            acc[3][0] += a.w * b.x; acc[3][1] += a.w * b.y;
        }
    }
    float mx0 = fmaxf(fmaxf(acc[0][0], acc[1][0]), fmaxf(acc[2][0], acc[3][0])) + bmp[n0 + tn2];
    float mx1 = fmaxf(fmaxf(acc[0][1], acc[1][1]), fmaxf(acc[2][1], acc[3][1])) + bmp[n0 + tn2 + 1];
    float2 o; o.x = tanh_fast(mx0); o.y = tanh_fast(mx1);
    *(float2*)(pooled + (size_t)(bx * 16 + tm) * HH + n0 + tn2) = o;
}

// ---------------------------------------------------------------------------
// logits tile: out[b][p] = pooled[b] @ Wsm^T + bsm, rows [bx*16,+16) x
// cols [by*32,+32); fp32 VALU.
// ---------------------------------------------------------------------------
__device__ __forceinline__ void sm_tile(char* smem, int tid, int bx, int by,
    const float* __restrict__ pooled, const float* __restrict__ Wsm,
    const float* __restrict__ bsm, float* __restrict__ outp)
{
    float* As = (float*)smem;            // [32][16]
    float* Bs = (float*)(smem + 2048);   // [32][32]
    const int tm = tid & 15;
    const int tn = tid >> 4;
    const int n0 = by * 32;
    const int ara = tid >> 4;
    const int aka = (tid & 15) * 2;
    const int brb = tid >> 3;
    const int bkb = (tid & 7) * 4;
    const float* arow = pooled + (size_t)(bx * 16 + ara) * HH + aka;
    const float* brow = Wsm + (size_t)(n0 + brb) * HH + bkb;
    float a0 = 0.f, a1 = 0.f;
    const int tn2 = tn * 2;
    for (int k0 = 0; k0 < HH; k0 += 32) {
        __syncthreads();
        float2 av = *(const float2*)(arow + k0);
        float4 bv = *(const float4*)(brow + k0);
        As[(aka + 0) * 16 + ara] = av.x; As[(aka + 1) * 16 + ara] = av.y;
        Bs[(bkb + 0) * 32 + brb] = bv.x; Bs[(bkb + 1) * 32 + brb] = bv.y;
        Bs[(bkb + 2) * 32 + brb] = bv.z; Bs[(bkb + 3) * 32 + brb] = bv.w;
        __syncthreads();
        #pragma unroll
        for (int k = 0; k < 32; ++k) {
            float a = As[k * 16 + tm];
            a0 += a * Bs[k * 32 + tn2];
            a1 += a * Bs[k * 32 + tn2 + 1];
        }
    }
    float2 o; o.x = a0 + bsm[n0 + tn2]; o.y = a1 + bsm[n0 + tn2 + 1];
    *(float2*)(outp + (size_t)(bx * 16 + tm) * PP + n0 + tn2) = o;
}

// ---------------------------------------------------------------------------
// Persistent encoder: both LSTM phases (128+128 steps) in ONE launch.
// Grid 256 blocks; XCD swizzle; group barrier between steps.
// ---------------------------------------------------------------------------
__global__ __launch_bounds__(256, 2) void persist_enc(
    const int* __restrict__ tokens_in, const int* __restrict__ lengths_in,
    const int* __restrict__ tokens_out, const int* __restrict__ lengths_out,
    const ushort_t* __restrict__ Whi_in, const ushort_t* __restrict__ Wlo_in,
    const ushort_t* __restrict__ Whi_out, const ushort_t* __restrict__ Wlo_out,
    const float* __restrict__ embW_in, const float* __restrict__ embW_out,
    float* h_a, ushort_t* hhi_a, ushort_t* hlo_a,
    float* h_b, ushort_t* hhi_b, ushort_t* hlo_b,
    float* c_st, unsigned int* barcnt)
{
    __shared__ __align__(16) char smem[36864];
    const int tid = threadIdx.x;
    const int id = blockIdx.x;
    const int by = (id & 7) + 8 * ((id >> 3) & 3);
    const int bx = id >> 5;
    unsigned int* cnt = barcnt + bx * 32;
    unsigned int barv = 0;

    float* hc = h_a;  ushort_t* hic = hhi_a;  ushort_t* lcc = hlo_a;
    float* hn = h_b;  ushort_t* hin = hhi_b;  ushort_t* lnn = hlo_b;

    for (int ph = 0; ph < 2; ++ph) {
        const int* tok = ph ? tokens_out : tokens_in;
        const int* len = ph ? lengths_out : lengths_in;
        const ushort_t* Wh = ph ? Whi_out : Whi_in;
        const ushort_t* Wl = ph ? Wlo_out : Wlo_in;
        const float* iE = ph ? embW_out : embW_in;
        for (int t = 0; t < 128; ++t) {
            lstm_tile(smem, tid, bx, by, hc, hic, lcc, hn, hin, lnn, c_st,
                      Wh, Wl, iE, tok, len, t);
            { float* tf = hc; hc = hn; hn = tf; }
            { ushort_t* th = hic; hic = hin; hin = th; }
            { ushort_t* tl = lcc; lcc = lnn; lnn = tl; }
            ++barv;
            group_bar(cnt, 32u * barv);
        }
    }
}

// ---------------------------------------------------------------------------
// Persistent decoder: 16 x (lstm step -> pool -> softmax) in ONE launch.
// ---------------------------------------------------------------------------
__global__ __launch_bounds__(256, 2) void persist_dec(
    const ushort_t* __restrict__ Whi_p, const ushort_t* __restrict__ Wlo_p,
    const float* __restrict__ u_p,
    const float* __restrict__ W_mp, const float* __restrict__ b_mp,
    const float* __restrict__ W_sm, const float* __restrict__ b_sm,
    float* h_a, ushort_t* hhi_a, ushort_t* hlo_a,
    float* h_b, ushort_t* hhi_b, ushort_t* hlo_b,
    float* c_st, float* pooled, float* out, unsigned int* barcnt)
{
    __shared__ __align__(16) char smem[36864];
    const int tid = threadIdx.x;
    const int id = blockIdx.x;
    const int by = (id & 7) + 8 * ((id >> 3) & 3);
    const int bx = id >> 5;
    unsigned int* cnt = barcnt + bx * 32;
    unsigned int barv = 0;

    float* hc = h_a;  ushort_t* hic = hhi_a;  ushort_t* lcc = hlo_a;
    float* hn = h_b;  ushort_t* hin = hhi_b;  ushort_t* lnn = hlo_b;

    for (int t = 0; t < 16; ++t) {
        lstm_tile(smem, tid, bx, by, hc, hic, lcc, hn, hin, lnn, c_st,
                  Whi_p, Wlo_p, u_p, nullptr, nullptr, t);
        { float* tf = hc; hc = hn; hn = tf; }
        { ushort_t* th = hic; hic = hin; hin = th; }
        { ushort_t* tl = lcc; lcc = lnn; lnn = tl; }
        ++barv; group_bar(cnt, 32u * barv);

        pool_tile(smem, tid, bx, by, hc, W_mp, b_mp, pooled);
        ++barv; group_bar(cnt, 32u * barv);

        sm_tile(smem, tid, bx, by, pooled, W_sm, b_sm, out + (size_t)t * (BB * PP));
        ++barv; group_bar(cnt, 32u * barv);
    }
}

// ---------------------------------------------------------------------------
// Generic fp32 C[M][N] = A[M][K] @ W[N][K]^T + bias[N]
// grid (M/32, N/64), block 256; per thread 4x2.
// ---------------------------------------------------------------------------
__global__ __launch_bounds__(256) void gemm_bias(
    const float* __restrict__ A, const float* __restrict__ W,
    const float* __restrict__ bias, float* __restrict__ C,
    int N, int K)
{
    __shared__ __align__(16) float As[16][32];
    __shared__ __align__(16) float Bs[16][64];
    const int tid = threadIdx.x;
    const int tm = tid & 7;
    const int tn = tid >> 3;
    const int m0 = blockIdx.x * 32, n0 = blockIdx.y * 64;
    const int am = tid >> 3;
    const int ak = (tid & 7) * 2;
    const int br = tid >> 2;
    const int bk = (tid & 3) * 4;
    const float* arow = A + (size_t)(m0 + am) * K;
    const float* brow = W + (size_t)(n0 + br) * K;
    float acc[4][2] = {};
    const int tm4 = tm * 4, tn2 = tn * 2;

    for (int k0 = 0; k0 < K; k0 += 16) {
        __syncthreads();
        float2 av = *(const float2*)(arow + k0 + ak);
        float4 bv = *(const float4*)(brow + k0 + bk);
        As[ak][am] = av.x; As[ak + 1][am] = av.y;
        Bs[bk][br] = bv.x; Bs[bk + 1][br] = bv.y;
        Bs[bk + 2][br] = bv.z; Bs[bk + 3][br] = bv.w;
        __syncthreads();
        #pragma unroll
        for (int k = 0; k < 16; ++k) {
            float4 a = *(const float4*)&As[k][tm4];
            float2 b = *(const float2*)&Bs[k][tn2];
            acc[0][0] += a.x * b.x; acc[0][1] += a.x * b.y;
            acc[1][0] += a.y * b.x; acc[1][1] += a.y * b.y;
            acc[2][0] += a.z * b.x; acc[2][1] += a.z * b.y;
            acc[3][0] += a.w * b.x; acc[3][1] += a.w * b.y;
        }
    }
    float b0 = bias[n0 + tn2], b1 = bias[n0 + tn2 + 1];
    #pragma unroll
    for (int mi = 0; mi < 4; ++mi) {
        float2 o;
        o.x = acc[mi][0] + b0;
        o.y = acc[mi][1] + b1;
        *(float2*)(C + (size_t)(m0 + tm4 + mi) * N + n0 + tn2) = o;
    }
}

extern "C" void kernel_launch(void* const* d_in, const int* in_sizes, int n_in,
                              void* d_out, int out_size, void* d_ws, size_t ws_size,
                              hipStream_t stream)
{
    const int*   tokens_in   = (const int*)d_in[0];
    const int*   lengths_in  = (const int*)d_in[1];
    const int*   tokens_out  = (const int*)d_in[2];
    const int*   lengths_out = (const int*)d_in[3];
    const float* embedding   = (const float*)d_in[4];
    const float* W_ih_in     = (const float*)d_in[5];
    const float* W_hh_in     = (const float*)d_in[6];
    const float* b_in        = (const float*)d_in[7];
    const float* W_ih_out    = (const float*)d_in[8];
    const float* W_hh_out    = (const float*)d_in[9];
    const float* b_out       = (const float*)d_in[10];
    const float* W_ih_p      = (const float*)d_in[11];
    const float* W_hh_p      = (const float*)d_in[12];
    const float* b_p         = (const float*)d_in[13];
    const float* W_mp        = (const float*)d_in[14];
    const float* b_mp        = (const float*)d_in[15];
    const float* W_sm        = (const float*)d_in[16];
    const float* b_sm        = (const float*)d_in[17];
    float* out = (float*)d_out;

    // workspace layout (float units); ~74 MB total
    float* ws = (float*)d_ws;
    float* h_a      = ws;                  // 524288
    float* h_b      = ws + 524288;         // 524288
    float* c_st     = ws + 1048576;        // 524288
    float* embW_in  = ws + 1572864;        // 524288
    float* embW_out = ws + 2097152;        // 524288
    float* u_p      = ws + 2621440;        // 2097152
    float* pooled   = ws + 4718592;        // 131072
    ushort_t* hhi_a = (ushort_t*)(ws + 4849664);   // 524288 bf16 each
    ushort_t* hlo_a = (ushort_t*)(ws + 5111808);
    ushort_t* hhi_b = (ushort_t*)(ws + 5373952);
    ushort_t* hlo_b = (ushort_t*)(ws + 5636096);
    ushort_t* Whi_in  = (ushort_t*)(ws + 5898240); // 4194304 bf16 each
    ushort_t* Wlo_in  = (ushort_t*)(ws + 7995392);
    ushort_t* Whi_out = (ushort_t*)(ws + 10092544);
    ushort_t* Wlo_out = (ushort_t*)(ws + 12189696);
    ushort_t* Whi_p   = (ushort_t*)(ws + 14286848);
    ushort_t* Wlo_p   = (ushort_t*)(ws + 16384000);
    unsigned int* barcnt = (unsigned int*)(ws + 18481152); // 512 uints

    // zero h0, c0, h0's bf16 hi/lo (hhi_a/hlo_a adjacent), barrier counters
    fillz<<<2048, 256, 0, stream>>>(h_a, 524288);
    fillz<<<2048, 256, 0, stream>>>(c_st, 524288);
    fillz<<<2048, 256, 0, stream>>>(ws + 4849664, 524288);
    fillz<<<2, 256, 0, stream>>>((float*)barcnt, 512);

    // split the three recurrent weight matrices into bf16 hi/lo
    split_w<<<16384, 256, 0, stream>>>(W_hh_in,  Whi_in,  Wlo_in,  4194304);
    split_w<<<16384, 256, 0, stream>>>(W_hh_out, Whi_out, Wlo_out, 4194304);
    split_w<<<16384, 256, 0, stream>>>(W_hh_p,   Whi_p,   Wlo_p,   4194304);

    // embW = embedding @ W_ih^T + b  (x @ W_ih collapses to a gather)
    gemm_bias<<<dim3(4, 64), 256, 0, stream>>>(embedding, W_ih_in, b_in, embW_in, 4096, 128);
    gemm_bias<<<dim3(4, 64), 256, 0, stream>>>(embedding, W_ih_out, b_out, embW_out, 4096, 128);

    // both encoder phases in one persistent launch (256 steps, group barriers)
    persist_enc<<<256, 256, 0, stream>>>(
        tokens_in, lengths_in, tokens_out, lengths_out,
        Whi_in, Wlo_in, Whi_out, Wlo_out, embW_in, embW_out,
        h_a, hhi_a, hlo_a, h_b, hhi_b, hlo_b, c_st, barcnt);

    // u_p = prev_h @ W_ih_p^T + b_p (prev_h = h_a after 256 swaps), fp32
    gemm_bias<<<dim3(16, 64), 256, 0, stream>>>(h_a, W_ih_p, b_p, u_p, 4096, 1024);

    // decoder: 16 x (lstm -> pool -> softmax) in one persistent launch
    persist_dec<<<256, 256, 0, stream>>>(
        Whi_p, Wlo_p, u_p, W_mp, b_mp, W_sm, b_sm,
        h_a, hhi_a, hlo_a, h_b, hhi_b, hlo_b, c_st, pooled, out, barcnt + 256);
}

// Round 6
// 17790.623 us; speedup vs baseline: 1.1493x; 1.1493x over previous
//
#include <hip/hip_runtime.h>

#define FF 512
#define HH 1024
#define LL 128
#define BB 128
#define PP 1024

typedef short short8 __attribute__((ext_vector_type(8)));
typedef float floatx4 __attribute__((ext_vector_type(4)));
typedef unsigned short ushort_t;

__device__ __forceinline__ float sigm(float x) {
    return 1.0f / (1.0f + __expf(-x));
}
// overflow-safe tanh: exp(-2|x|) underflows to 0 for large |x| -> +-1
__device__ __forceinline__ float tanh_fast(float x) {
    float ax = fabsf(x);
    float e = __expf(-2.0f * ax);
    float r = (1.0f - e) / (1.0f + e);
    return copysignf(r, x);
}

__device__ __forceinline__ unsigned short bf16_rtne(float x) {
    unsigned int u = __float_as_uint(x);
    return (unsigned short)((u + 0x7FFFu + ((u >> 16) & 1u)) >> 16);
}
__device__ __forceinline__ void split_bf16(float x, unsigned short& hi, unsigned short& lo) {
    hi = bf16_rtne(x);
    float hf = __uint_as_float(((unsigned int)hi) << 16);
    lo = bf16_rtne(x - hf);
}

// ---- agent-scope (cross-XCD coherent, cache-bypassing) accessors ----------
__device__ __forceinline__ uint4 ald4(const ushort_t* p) {
    const unsigned int* q = (const unsigned int*)p;
    uint4 r;
    r.x = __hip_atomic_load(q + 0, __ATOMIC_RELAXED, __HIP_MEMORY_SCOPE_AGENT);
    r.y = __hip_atomic_load(q + 1, __ATOMIC_RELAXED, __HIP_MEMORY_SCOPE_AGENT);
    r.z = __hip_atomic_load(q + 2, __ATOMIC_RELAXED, __HIP_MEMORY_SCOPE_AGENT);
    r.w = __hip_atomic_load(q + 3, __ATOMIC_RELAXED, __HIP_MEMORY_SCOPE_AGENT);
    return r;
}
__device__ __forceinline__ float aldf(const float* p) {
    return __hip_atomic_load(p, __ATOMIC_RELAXED, __HIP_MEMORY_SCOPE_AGENT);
}
__device__ __forceinline__ void astf(float* p, float v) {
    __hip_atomic_store(p, v, __ATOMIC_RELAXED, __HIP_MEMORY_SCOPE_AGENT);
}
__device__ __forceinline__ void astu(ushort_t* p, unsigned int v) {
    __hip_atomic_store((unsigned int*)p, v, __ATOMIC_RELAXED, __HIP_MEMORY_SCOPE_AGENT);
}

__global__ void fillz(float* p, int n) {
    int i = blockIdx.x * blockDim.x + threadIdx.x;
    if (i < n) p[i] = 0.0f;
}

// fp32 [n] -> bf16 hi/lo [n]
__global__ void split_w(const float* __restrict__ W, ushort_t* __restrict__ hi,
                        ushort_t* __restrict__ lo, int n) {
    int i = blockIdx.x * blockDim.x + threadIdx.x;
    if (i < n) {
        unsigned short h, l;
        split_bf16(W[i], h, l);
        hi[i] = h; lo[i] = l;
    }
}

// ---------------------------------------------------------------------------
// 32-block group barrier with NO cache invalidation (the R5 version's
// agent-scope acquire fence lowered to buffer_inv -> evicted W from L2 every
// step -> 16 MB HBM refetch/step, the measured 4 GB FETCH_SIZE).
// Release on the add = waitcnt drain (+ at worst an L2 *writeback*, which
// keeps clean W lines). Cross-block data visibility is handled by the
// agent-scope bypass loads/stores above, so the consumer needs no acquire.
// Deadlock-safe: grid 256 = 1 block/CU, always co-resident.
// ---------------------------------------------------------------------------
__device__ __forceinline__ void group_bar(unsigned int* cnt, unsigned int target) {
    __syncthreads();
    if (threadIdx.x == 0) {
        __hip_atomic_fetch_add(cnt, 1u, __ATOMIC_RELEASE, __HIP_MEMORY_SCOPE_AGENT);
        while (__hip_atomic_load(cnt, __ATOMIC_RELAXED, __HIP_MEMORY_SCOPE_AGENT) < target)
            __builtin_amdgcn_s_sleep(2);
    }
    __syncthreads();
    asm volatile("" ::: "memory");
}

// ---------------------------------------------------------------------------
// One LSTM timestep tile (64 f-rows x 32 cols x 4 gates), bf16-split MFMA:
// g = init + h @ W_hh^T via h_hi*W_hi + h_lo*W_hi + h_hi*W_lo.
// W (B operand) via NORMAL loads -> stays L2-resident across all steps now.
// h (A operand + epilogue) via agent-scope bypass accessors (fresh cross-XCD).
// c is block-private -> normal cached accesses.
// ---------------------------------------------------------------------------
__device__ __forceinline__ void lstm_tile(
    char* smem, int tid, int bx, int by,
    const float* __restrict__ h_in,
    const ushort_t* __restrict__ hhi, const ushort_t* __restrict__ hlo,
    float* __restrict__ h_out,
    ushort_t* __restrict__ hhi_o, ushort_t* __restrict__ hlo_o,
    float* __restrict__ c_st,
    const ushort_t* __restrict__ Whi, const ushort_t* __restrict__ Wlo,
    const float* __restrict__ initE,
    const int* __restrict__ tokens, const int* __restrict__ lengths, int t)
{
    char* As_hi = smem;                  // 8 KB: 64 rows x 8 slots x 16 B
    char* As_lo = smem + 8192;
    float* Gx = (float*)smem;            // epilogue reuse: [4][64][36] fp32

    const int w = tid >> 6;              // wave index = gate
    const int l = tid & 63;
    const int q = l >> 4;                // k-quad 0..3
    const int fr = l & 15;               // fragment row/col
    const int fbase = bx * 64;
    const int n0 = by * 32;

    const int ar = tid >> 2;
    const int s0 = tid & 3;
    const size_t a_goff = (size_t)(fbase + ar) * HH + s0 * 8;

    const size_t brow0 = ((size_t)(w * HH) + n0 + 0 * 16 + fr) * HH + q * 8;
    const size_t brow1 = ((size_t)(w * HH) + n0 + 1 * 16 + fr) * HH + q * 8;

    floatx4 acc[4][2];
    #pragma unroll
    for (int m = 0; m < 4; ++m)
        #pragma unroll
        for (int n = 0; n < 2; ++n) acc[m][n] = (floatx4)(0.0f);

    uint4 pa_h0 = ald4(hhi + a_goff);
    uint4 pa_h1 = ald4(hhi + a_goff + 32);
    uint4 pa_l0 = ald4(hlo + a_goff);
    uint4 pa_l1 = ald4(hlo + a_goff + 32);

    short8 Bh[2][2][2], Bl[2][2][2];
    #pragma unroll
    for (int kk = 0; kk < 2; ++kk) {
        Bh[0][0][kk] = *(const short8*)(Whi + brow0 + kk * 32);
        Bh[0][1][kk] = *(const short8*)(Whi + brow1 + kk * 32);
        Bl[0][0][kk] = *(const short8*)(Wlo + brow0 + kk * 32);
        Bl[0][1][kk] = *(const short8*)(Wlo + brow1 + kk * 32);
    }

    const int sw0 = (s0 + ar) & 7;
    const int sw1 = ((s0 + 4) + ar) & 7;

    #pragma unroll 2
    for (int kc = 0; kc < 16; ++kc) {
        const int cur = kc & 1, nxt = cur ^ 1;
        __syncthreads();
        ((uint4*)As_hi)[ar * 8 + sw0] = pa_h0;
        ((uint4*)As_hi)[ar * 8 + sw1] = pa_h1;
        ((uint4*)As_lo)[ar * 8 + sw0] = pa_l0;
        ((uint4*)As_lo)[ar * 8 + sw1] = pa_l1;
        __syncthreads();

        if (kc < 15) {
            const int k0 = (kc + 1) * 64;
            pa_h0 = ald4(hhi + a_goff + k0);
            pa_h1 = ald4(hhi + a_goff + k0 + 32);
            pa_l0 = ald4(hlo + a_goff + k0);
            pa_l1 = ald4(hlo + a_goff + k0 + 32);
            #pragma unroll
            for (int kk = 0; kk < 2; ++kk) {
                Bh[nxt][0][kk] = *(const short8*)(Whi + brow0 + k0 + kk * 32);
                Bh[nxt][1][kk] = *(const short8*)(Whi + brow1 + k0 + kk * 32);
                Bl[nxt][0][kk] = *(const short8*)(Wlo + brow0 + k0 + kk * 32);
                Bl[nxt][1][kk] = *(const short8*)(Wlo + brow1 + k0 + kk * 32);
            }
        }

        #pragma unroll
        for (int m = 0; m < 4; ++m) {
            const int r = m * 16 + fr;
            short8 ah0 = *(const short8*)(As_hi + (r * 8 + ((0 * 4 + q + r) & 7)) * 16);
            short8 ah1 = *(const short8*)(As_hi + (r * 8 + ((1 * 4 + q + r) & 7)) * 16);
            short8 al0 = *(const short8*)(As_lo + (r * 8 + ((0 * 4 + q + r) & 7)) * 16);
            short8 al1 = *(const short8*)(As_lo + (r * 8 + ((1 * 4 + q + r) & 7)) * 16);
            #pragma unroll
            for (int n = 0; n < 2; ++n) {
                acc[m][n] = __builtin_amdgcn_mfma_f32_16x16x32_bf16(ah0, Bh[cur][n][0], acc[m][n], 0, 0, 0);
                acc[m][n] = __builtin_amdgcn_mfma_f32_16x16x32_bf16(al0, Bh[cur][n][0], acc[m][n], 0, 0, 0);
                acc[m][n] = __builtin_amdgcn_mfma_f32_16x16x32_bf16(ah0, Bl[cur][n][0], acc[m][n], 0, 0, 0);
                acc[m][n] = __builtin_amdgcn_mfma_f32_16x16x32_bf16(ah1, Bh[cur][n][1], acc[m][n], 0, 0, 0);
                acc[m][n] = __builtin_amdgcn_mfma_f32_16x16x32_bf16(al1, Bh[cur][n][1], acc[m][n], 0, 0, 0);
                acc[m][n] = __builtin_amdgcn_mfma_f32_16x16x32_bf16(ah1, Bl[cur][n][1], acc[m][n], 0, 0, 0);
            }
        }
    }

    // --- gate exchange (C/D: col = fr, row = q*4 + reg); row stride 36 ---
    __syncthreads();
    #pragma unroll
    for (int m = 0; m < 4; ++m)
        #pragma unroll
        for (int n = 0; n < 2; ++n)
            #pragma unroll
            for (int r = 0; r < 4; ++r)
                Gx[(w * 64 + m * 16 + q * 4 + r) * 36 + n * 16 + fr] = acc[m][n][r];
    __syncthreads();

    // --- fused cell update: thread -> (row rr, 8 consecutive cols) ---
    const int rr = tid >> 2;
    const int c0 = (tid & 3) * 8;
    const int f = fbase + rr;
    const int gc = n0 + c0;
    const size_t gidx = (size_t)f * HH + gc;
    const float* ib = tokens ? (initE + (size_t)tokens[f * LL + t] * 4096)
                             : (initE + (size_t)f * 4096);
    const bool upd = lengths ? (t < lengths[f]) : true;

    float gv[4][8];
    #pragma unroll
    for (int g = 0; g < 4; ++g) {
        float4 x0 = *(const float4*)&Gx[(g * 64 + rr) * 36 + c0];
        float4 x1 = *(const float4*)&Gx[(g * 64 + rr) * 36 + c0 + 4];
        const float4 i0 = *(const float4*)(ib + g * 1024 + gc);
        const float4 i1 = *(const float4*)(ib + g * 1024 + gc + 4);
        gv[g][0] = x0.x + i0.x; gv[g][1] = x0.y + i0.y;
        gv[g][2] = x0.z + i0.z; gv[g][3] = x0.w + i0.w;
        gv[g][4] = x1.x + i1.x; gv[g][5] = x1.y + i1.y;
        gv[g][6] = x1.z + i1.z; gv[g][7] = x1.w + i1.w;
    }
    // c is block-private: normal cached access
    float4 cv0 = *(const float4*)(c_st + gidx);
    float4 cv1 = *(const float4*)(c_st + gidx + 4);
    float cold[8] = {cv0.x, cv0.y, cv0.z, cv0.w, cv1.x, cv1.y, cv1.z, cv1.w};
    float hold[8];
    #pragma unroll
    for (int j = 0; j < 8; ++j) hold[j] = aldf(h_in + gidx + j);

    float cw[8], hw[8];
    uint4 hiv, lov;
    #pragma unroll
    for (int j = 0; j < 8; ++j) {
        float cn = sigm(gv[1][j]) * cold[j] + sigm(gv[0][j]) * tanh_fast(gv[2][j]);
        float hn = sigm(gv[3][j]) * tanh_fast(cn);
        cw[j] = upd ? cn : cold[j];
        hw[j] = upd ? hn : hold[j];
        unsigned short hb, lb;
        split_bf16(hw[j], hb, lb);
        ((ushort_t*)&hiv)[j] = hb;
        ((ushort_t*)&lov)[j] = lb;
    }
    *(float4*)(c_st + gidx)     = make_float4(cw[0], cw[1], cw[2], cw[3]);
    *(float4*)(c_st + gidx + 4) = make_float4(cw[4], cw[5], cw[6], cw[7]);
    #pragma unroll
    for (int j = 0; j < 8; ++j) astf(h_out + gidx + j, hw[j]);
    #pragma unroll
    for (int k = 0; k < 4; ++k) {
        astu(hhi_o + gidx + 2 * k, ((unsigned int*)&hiv)[k]);
        astu(hlo_o + gidx + 2 * k, ((unsigned int*)&lov)[k]);
    }
}

// ---------------------------------------------------------------------------
// pooled[b][n] = tanh(max over 4 examples of h@Wmp^T + bmp); group-local
// tile: programs [bx*16,+16) x cols [by*32,+32). h read via agent loads
// (cross-block), Wmp normal (L2). Register prefetch hides L3 latency.
// ---------------------------------------------------------------------------
__device__ __forceinline__ void pool_tile(char* smem, int tid, int bx, int by,
    const float* __restrict__ h, const float* __restrict__ Wmp,
    const float* __restrict__ bmp, float* __restrict__ pooled)
{
    float* As = (float*)smem;            // [16][64]
    float* Bs = (float*)(smem + 4096);   // [16][32]
    const int tm = tid & 15;
    const int tn = tid >> 4;
    const int fbase = bx * 64, n0 = by * 32;
    const int ar = tid >> 2;
    const int ak = (tid & 3) * 4;
    const int br = tid >> 3;
    const int bk = (tid & 7) * 2;
    const float* arow = h + (size_t)(fbase + ar) * HH + ak;
    const float* brow = Wmp + (size_t)(n0 + br) * HH + bk;
    float acc[4][2] = {};
    const int tm4 = tm * 4, tn2 = tn * 2;

    float a0 = aldf(arow + 0), a1 = aldf(arow + 1), a2 = aldf(arow + 2), a3 = aldf(arow + 3);
    float2 bv = *(const float2*)brow;

    for (int k0 = 0; k0 < HH; k0 += 16) {
        __syncthreads();
        As[(ak + 0) * 64 + ar] = a0; As[(ak + 1) * 64 + ar] = a1;
        As[(ak + 2) * 64 + ar] = a2; As[(ak + 3) * 64 + ar] = a3;
        Bs[(bk + 0) * 32 + br] = bv.x; Bs[(bk + 1) * 32 + br] = bv.y;
        __syncthreads();
        if (k0 + 16 < HH) {
            a0 = aldf(arow + k0 + 16); a1 = aldf(arow + k0 + 17);
            a2 = aldf(arow + k0 + 18); a3 = aldf(arow + k0 + 19);
            bv = *(const float2*)(brow + k0 + 16);
        }
        #pragma unroll
        for (int k = 0; k < 16; ++k) {
            float4 a = *(const float4*)&As[k * 64 + tm4];
            float2 b = *(const float2*)&Bs[k * 32 + tn2];
            acc[0][0] += a.x * b.x; acc[0][1] += a.x * b.y;
            acc[1][0] += a.y * b.x; acc[1][1] += a.y * b.y;
            acc[2][0] += a.z * b.x; acc[2][1] += a.z * b.y;
            acc[3][0] += a.w * b.x; acc[3][1] += a.w * b.y;
        }
    }
    float mx0 = fmaxf(fmaxf(acc[0][0], acc[1][0]), fmaxf(acc[2][0], acc[3][0])) + bmp[n0 + tn2];
    float mx1 = fmaxf(fmaxf(acc[0][1], acc[1][1]), fmaxf(acc[2][1], acc[3][1])) + bmp[n0 + tn2 + 1];
    float* pp = pooled + (size_t)(bx * 16 + tm) * HH + n0 + tn2;
    astf(pp + 0, tanh_fast(mx0));
    astf(pp + 1, tanh_fast(mx1));
}

// ---------------------------------------------------------------------------
// logits tile: out[b][p] = pooled[b] @ Wsm^T + bsm, rows [bx*16,+16) x
// cols [by*32,+32). pooled via agent loads (cross-block).
// ---------------------------------------------------------------------------
__device__ __forceinline__ void sm_tile(char* smem, int tid, int bx, int by,
    const float* __restrict__ pooled, const float* __restrict__ Wsm,
    const float* __restrict__ bsm, float* __restrict__ outp)
{
    float* As = (float*)smem;            // [32][16]
    float* Bs = (float*)(smem + 2048);   // [32][32]
    const int tm = tid & 15;
    const int tn = tid >> 4;
    const int n0 = by * 32;
    const int ara = tid >> 4;
    const int aka = (tid & 15) * 2;
    const int brb = tid >> 3;
    const int bkb = (tid & 7) * 4;
    const float* arow = pooled + (size_t)(bx * 16 + ara) * HH + aka;
    const float* brow = Wsm + (size_t)(n0 + brb) * HH + bkb;
    float a0 = 0.f, a1 = 0.f;
    const int tn2 = tn * 2;

    float p0 = aldf(arow + 0), p1 = aldf(arow + 1);
    float4 bv = *(const float4*)brow;

    for (int k0 = 0; k0 < HH; k0 += 32) {
        __syncthreads();
        As[(aka + 0) * 16 + ara] = p0; As[(aka + 1) * 16 + ara] = p1;
        Bs[(bkb + 0) * 32 + brb] = bv.x; Bs[(bkb + 1) * 32 + brb] = bv.y;
        Bs[(bkb + 2) * 32 + brb] = bv.z; Bs[(bkb + 3) * 32 + brb] = bv.w;
        __syncthreads();
        if (k0 + 32 < HH) {
            p0 = aldf(arow + k0 + 32); p1 = aldf(arow + k0 + 33);
            bv = *(const float4*)(brow + k0 + 32);
        }
        #pragma unroll
        for (int k = 0; k < 32; ++k) {
            float a = As[k * 16 + tm];
            a0 += a * Bs[k * 32 + tn2];
            a1 += a * Bs[k * 32 + tn2 + 1];
        }
    }
    float2 o; o.x = a0 + bsm[n0 + tn2]; o.y = a1 + bsm[n0 + tn2 + 1];
    *(float2*)(outp + (size_t)(bx * 16 + tm) * PP + n0 + tn2) = o;
}

// ---------------------------------------------------------------------------
// Persistent encoder: both LSTM phases (128+128 steps) in ONE launch.
// ---------------------------------------------------------------------------
__global__ __launch_bounds__(256, 2) void persist_enc(
    const int* __restrict__ tokens_in, const int* __restrict__ lengths_in,
    const int* __restrict__ tokens_out, const int* __restrict__ lengths_out,
    const ushort_t* __restrict__ Whi_in, const ushort_t* __restrict__ Wlo_in,
    const ushort_t* __restrict__ Whi_out, const ushort_t* __restrict__ Wlo_out,
    const float* __restrict__ embW_in, const float* __restrict__ embW_out,
    float* h_a, ushort_t* hhi_a, ushort_t* hlo_a,
    float* h_b, ushort_t* hhi_b, ushort_t* hlo_b,
    float* c_st, unsigned int* barcnt)
{
    __shared__ __align__(16) char smem[36864];
    const int tid = threadIdx.x;
    const int id = blockIdx.x;
    const int by = (id & 7) + 8 * ((id >> 3) & 3);
    const int bx = id >> 5;
    unsigned int* cnt = barcnt + bx * 32;
    unsigned int barv = 0;

    float* hc = h_a;  ushort_t* hic = hhi_a;  ushort_t* lcc = hlo_a;
    float* hn = h_b;  ushort_t* hin = hhi_b;  ushort_t* lnn = hlo_b;

    for (int ph = 0; ph < 2; ++ph) {
        const int* tok = ph ? tokens_out : tokens_in;
        const int* len = ph ? lengths_out : lengths_in;
        const ushort_t* Wh = ph ? Whi_out : Whi_in;
        const ushort_t* Wl = ph ? Wlo_out : Wlo_in;
        const float* iE = ph ? embW_out : embW_in;
        for (int t = 0; t < 128; ++t) {
            lstm_tile(smem, tid, bx, by, hc, hic, lcc, hn, hin, lnn, c_st,
                      Wh, Wl, iE, tok, len, t);
            { float* tf = hc; hc = hn; hn = tf; }
            { ushort_t* th = hic; hic = hin; hin = th; }
            { ushort_t* tl = lcc; lcc = lnn; lnn = tl; }
            ++barv;
            group_bar(cnt, 32u * barv);
        }
    }
}

// ---------------------------------------------------------------------------
// Persistent decoder: 16 x (lstm step -> pool -> softmax) in ONE launch.
// ---------------------------------------------------------------------------
__global__ __launch_bounds__(256, 2) void persist_dec(
    const ushort_t* __restrict__ Whi_p, const ushort_t* __restrict__ Wlo_p,
    const float* __restrict__ u_p,
    const float* __restrict__ W_mp, const float* __restrict__ b_mp,
    const float* __restrict__ W_sm, const float* __restrict__ b_sm,
    float* h_a, ushort_t* hhi_a, ushort_t* hlo_a,
    float* h_b, ushort_t* hhi_b, ushort_t* hlo_b,
    float* c_st, float* pooled, float* out, unsigned int* barcnt)
{
    __shared__ __align__(16) char smem[36864];
    const int tid = threadIdx.x;
    const int id = blockIdx.x;
    const int by = (id & 7) + 8 * ((id >> 3) & 3);
    const int bx = id >> 5;
    unsigned int* cnt = barcnt + bx * 32;
    unsigned int barv = 0;

    float* hc = h_a;  ushort_t* hic = hhi_a;  ushort_t* lcc = hlo_a;
    float* hn = h_b;  ushort_t* hin = hhi_b;  ushort_t* lnn = hlo_b;

    for (int t = 0; t < 16; ++t) {
        lstm_tile(smem, tid, bx, by, hc, hic, lcc, hn, hin, lnn, c_st,
                  Whi_p, Wlo_p, u_p, nullptr, nullptr, t);
        { float* tf = hc; hc = hn; hn = tf; }
        { ushort_t* th = hic; hic = hin; hin = th; }
        { ushort_t* tl = lcc; lcc = lnn; lnn = tl; }
        ++barv; group_bar(cnt, 32u * barv);

        pool_tile(smem, tid, bx, by, hc, W_mp, b_mp, pooled);
        ++barv; group_bar(cnt, 32u * barv);

        sm_tile(smem, tid, bx, by, pooled, W_sm, b_sm, out + (size_t)t * (BB * PP));
        ++barv; group_bar(cnt, 32u * barv);
    }
}

// ---------------------------------------------------------------------------
// Generic fp32 C[M][N] = A[M][K] @ W[N][K]^T + bias[N]
// grid (M/32, N/64), block 256; per thread 4x2.
// ---------------------------------------------------------------------------
__global__ __launch_bounds__(256) void gemm_bias(
    const float* __restrict__ A, const float* __restrict__ W,
    const float* __restrict__ bias, float* __restrict__ C,
    int N, int K)
{
    __shared__ __align__(16) float As[16][32];
    __shared__ __align__(16) float Bs[16][64];
    const int tid = threadIdx.x;
    const int tm = tid & 7;
    const int tn = tid >> 3;
    const int m0 = blockIdx.x * 32, n0 = blockIdx.y * 64;
    const int am = tid >> 3;
    const int ak = (tid & 7) * 2;
    const int br = tid >> 2;
    const int bk = (tid & 3) * 4;
    const float* arow = A + (size_t)(m0 + am) * K;
    const float* brow = W + (size_t)(n0 + br) * K;
    float acc[4][2] = {};
    const int tm4 = tm * 4, tn2 = tn * 2;

    for (int k0 = 0; k0 < K; k0 += 16) {
        __syncthreads();
        float2 av = *(const float2*)(arow + k0 + ak);
        float4 bv = *(const float4*)(brow + k0 + bk);
        As[ak][am] = av.x; As[ak + 1][am] = av.y;
        Bs[bk][br] = bv.x; Bs[bk + 1][br] = bv.y;
        Bs[bk + 2][br] = bv.z; Bs[bk + 3][br] = bv.w;
        __syncthreads();
        #pragma unroll
        for (int k = 0; k < 16; ++k) {
            float4 a = *(const float4*)&As[k][tm4];
            float2 b = *(const float2*)&Bs[k][tn2];
            acc[0][0] += a.x * b.x; acc[0][1] += a.x * b.y;
            acc[1][0] += a.y * b.x; acc[1][1] += a.y * b.y;
            acc[2][0] += a.z * b.x; acc[2][1] += a.z * b.y;
            acc[3][0] += a.w * b.x; acc[3][1] += a.w * b.y;
        }
    }
    float b0 = bias[n0 + tn2], b1 = bias[n0 + tn2 + 1];
    #pragma unroll
    for (int mi = 0; mi < 4; ++mi) {
        float2 o;
        o.x = acc[mi][0] + b0;
        o.y = acc[mi][1] + b1;
        *(float2*)(C + (size_t)(m0 + tm4 + mi) * N + n0 + tn2) = o;
    }
}

extern "C" void kernel_launch(void* const* d_in, const int* in_sizes, int n_in,
                              void* d_out, int out_size, void* d_ws, size_t ws_size,
                              hipStream_t stream)
{
    const int*   tokens_in   = (const int*)d_in[0];
    const int*   lengths_in  = (const int*)d_in[1];
    const int*   tokens_out  = (const int*)d_in[2];
    const int*   lengths_out = (const int*)d_in[3];
    const float* embedding   = (const float*)d_in[4];
    const float* W_ih_in     = (const float*)d_in[5];
    const float* W_hh_in     = (const float*)d_in[6];
    const float* b_in        = (const float*)d_in[7];
    const float* W_ih_out    = (const float*)d_in[8];
    const float* W_hh_out    = (const float*)d_in[9];
    const float* b_out       = (const float*)d_in[10];
    const float* W_ih_p      = (const float*)d_in[11];
    const float* W_hh_p      = (const float*)d_in[12];
    const float* b_p         = (const float*)d_in[13];
    const float* W_mp        = (const float*)d_in[14];
    const float* b_mp        = (const float*)d_in[15];
    const float* W_sm        = (const float*)d_in[16];
    const float* b_sm        = (const float*)d_in[17];
    float* out = (float*)d_out;

    // workspace layout (float units); ~74 MB total
    float* ws = (float*)d_ws;
    float* h_a      = ws;                  // 524288
    float* h_b      = ws + 524288;         // 524288
    float* c_st     = ws + 1048576;        // 524288
    float* embW_in  = ws + 1572864;        // 524288
    float* embW_out = ws + 2097152;        // 524288
    float* u_p      = ws + 2621440;        // 2097152
    float* pooled   = ws + 4718592;        // 131072
    ushort_t* hhi_a = (ushort_t*)(ws + 4849664);   // 524288 bf16 each
    ushort_t* hlo_a = (ushort_t*)(ws + 5111808);
    ushort_t* hhi_b = (ushort_t*)(ws + 5373952);
    ushort_t* hlo_b = (ushort_t*)(ws + 5636096);
    ushort_t* Whi_in  = (ushort_t*)(ws + 5898240); // 4194304 bf16 each
    ushort_t* Wlo_in  = (ushort_t*)(ws + 7995392);
    ushort_t* Whi_out = (ushort_t*)(ws + 10092544);
    ushort_t* Wlo_out = (ushort_t*)(ws + 12189696);
    ushort_t* Whi_p   = (ushort_t*)(ws + 14286848);
    ushort_t* Wlo_p   = (ushort_t*)(ws + 16384000);
    unsigned int* barcnt = (unsigned int*)(ws + 18481152); // 512 uints

    // zero h0, c0, h0's bf16 hi/lo (hhi_a/hlo_a adjacent), barrier counters
    fillz<<<2048, 256, 0, stream>>>(h_a, 524288);
    fillz<<<2048, 256, 0, stream>>>(c_st, 524288);
    fillz<<<2048, 256, 0, stream>>>(ws + 4849664, 524288);
    fillz<<<2, 256, 0, stream>>>((float*)barcnt, 512);

    // split the three recurrent weight matrices into bf16 hi/lo
    split_w<<<16384, 256, 0, stream>>>(W_hh_in,  Whi_in,  Wlo_in,  4194304);
    split_w<<<16384, 256, 0, stream>>>(W_hh_out, Whi_out, Wlo_out, 4194304);
    split_w<<<16384, 256, 0, stream>>>(W_hh_p,   Whi_p,   Wlo_p,   4194304);

    // embW = embedding @ W_ih^T + b  (x @ W_ih collapses to a gather)
    gemm_bias<<<dim3(4, 64), 256, 0, stream>>>(embedding, W_ih_in, b_in, embW_in, 4096, 128);
    gemm_bias<<<dim3(4, 64), 256, 0, stream>>>(embedding, W_ih_out, b_out, embW_out, 4096, 128);

    // both encoder phases in one persistent launch (256 steps, group barriers)
    persist_enc<<<256, 256, 0, stream>>>(
        tokens_in, lengths_in, tokens_out, lengths_out,
        Whi_in, Wlo_in, Whi_out, Wlo_out, embW_in, embW_out,
        h_a, hhi_a, hlo_a, h_b, hhi_b, hlo_b, c_st, barcnt);

    // u_p = prev_h @ W_ih_p^T + b_p (prev_h = h_a after 256 swaps), fp32
    gemm_bias<<<dim3(16, 64), 256, 0, stream>>>(h_a, W_ih_p, b_p, u_p, 4096, 1024);

    // decoder: 16 x (lstm -> pool -> softmax) in one persistent launch
    persist_dec<<<256, 256, 0, stream>>>(
        Whi_p, Wlo_p, u_p, W_mp, b_mp, W_sm, b_sm,
        h_a, hhi_a, hlo_a, h_b, hhi_b, hlo_b, c_st, pooled, out, barcnt + 256);
}

// Round 9
// 11971.555 us; speedup vs baseline: 1.7080x; 1.4861x over previous
//
#include <hip/hip_runtime.h>

#define FF 512
#define HH 1024
#define LL 128
#define BB 128
#define PP 1024

typedef short short8 __attribute__((ext_vector_type(8)));
typedef float floatx4 __attribute__((ext_vector_type(4)));
typedef unsigned int uintx4 __attribute__((ext_vector_type(4)));
typedef unsigned int uintx2 __attribute__((ext_vector_type(2)));
typedef unsigned short ushort_t;

__device__ __forceinline__ float sigm(float x) {
    return 1.0f / (1.0f + __expf(-x));
}
__device__ __forceinline__ float tanh_fast(float x) {
    float ax = fabsf(x);
    float e = __expf(-2.0f * ax);
    float r = (1.0f - e) / (1.0f + e);
    return copysignf(r, x);
}
__device__ __forceinline__ unsigned short bf16_rtne(float x) {
    unsigned int u = __float_as_uint(x);
    return (unsigned short)((u + 0x7FFFu + ((u >> 16) & 1u)) >> 16);
}
__device__ __forceinline__ void split_bf16(float x, unsigned short& hi, unsigned short& lo) {
    hi = bf16_rtne(x);
    float hf = __uint_as_float(((unsigned int)hi) << 16);
    lo = bf16_rtne(x - hf);
}
__device__ __forceinline__ float bf2f(unsigned int v) { return __uint_as_float(v << 16); }

// ---- WIDE cross-XCD bypass ops (sc0 sc1 = coherent, no L1/L2 alloc) -------
// R6 used dword atomics: 4-16x request amplification (measured WRITE_SIZE
// 26.6 MB/step vs 6 true). These are 16 B/lane, lane-contiguous.
// NOTE (R8 compile fix): asm "v" constraints need NATIVE ext_vector types,
// not HIP's uint4 struct ("indirect register inputs" error).
__device__ __forceinline__ void bissue4(const void* p, uintx4& d) {
    asm volatile("global_load_dwordx4 %0, %1, off sc0 sc1" : "=v"(d) : "v"(p));
}
__device__ __forceinline__ void bwait4(uintx4& a, uintx4& b, uintx4& c, uintx4& d) {
    asm volatile("s_waitcnt vmcnt(0)" : "+v"(a), "+v"(b), "+v"(c), "+v"(d) :: "memory");
}
__device__ __forceinline__ void bload4x2(const void* p1, const void* p2, uintx4& a, uintx4& b) {
    asm volatile("global_load_dwordx4 %0, %2, off sc0 sc1\n\t"
                 "global_load_dwordx4 %1, %3, off sc0 sc1\n\t"
                 "s_waitcnt vmcnt(0)"
                 : "=v"(a), "=v"(b) : "v"(p1), "v"(p2) : "memory");
}
__device__ __forceinline__ uintx4 bload4(const void* p) {
    uintx4 r;
    asm volatile("global_load_dwordx4 %0, %1, off sc0 sc1\n\ts_waitcnt vmcnt(0)"
                 : "=v"(r) : "v"(p) : "memory");
    return r;
}
__device__ __forceinline__ void bstore4(void* p, uintx4 v) {
    asm volatile("global_store_dwordx4 %0, %1, off sc0 sc1" :: "v"(p), "v"(v) : "memory");
}
__device__ __forceinline__ void bstore2(void* p, uintx2 v) {
    asm volatile("global_store_dwordx2 %0, %1, off sc0 sc1" :: "v"(p), "v"(v) : "memory");
}
// non-temporal float4 load (no L2 allocation -> protects W residency).
__device__ __forceinline__ float4 ntl4(const float* p) {
    floatx4 v = __builtin_nontemporal_load((const floatx4*)p);
    return make_float4(v.x, v.y, v.z, v.w);
}

__global__ void fillz(float* p, int n) {
    int i = blockIdx.x * blockDim.x + threadIdx.x;
    if (i < n) p[i] = 0.0f;
}

__global__ void split_w(const float* __restrict__ W, ushort_t* __restrict__ hi,
                        ushort_t* __restrict__ lo, int n) {
    int i = blockIdx.x * blockDim.x + threadIdx.x;
    if (i < n) {
        unsigned short h, l;
        split_bf16(W[i], h, l);
        hi[i] = h; lo[i] = l;
    }
}

// ---------------------------------------------------------------------------
// 32-block group barrier, NO cache maintenance at all. Bypass stores are
// drained by __syncthreads (full vmcnt drain, all waves); cross-block data
// moves only via sc0/sc1 bypass ops so no acquire/invalidate is needed.
// ---------------------------------------------------------------------------
__device__ __forceinline__ void group_bar(unsigned int* cnt, unsigned int target) {
    __syncthreads();   // emits s_waitcnt vmcnt(0)+lgkmcnt(0) per wave, then s_barrier
    if (threadIdx.x == 0) {
        __hip_atomic_fetch_add(cnt, 1u, __ATOMIC_RELAXED, __HIP_MEMORY_SCOPE_AGENT);
        while (__hip_atomic_load(cnt, __ATOMIC_RELAXED, __HIP_MEMORY_SCOPE_AGENT) < target)
            __builtin_amdgcn_s_sleep(2);
    }
    __syncthreads();
    asm volatile("" ::: "memory");
}

// ---------------------------------------------------------------------------
// One LSTM timestep tile (64 f x 32 cols x 4 gates), bf16-split MFMA.
// A (h bf16 hi/lo): bypass asm loads (issue before MFMA, wait next chunk).
// W: normal cached (L2-resident per XCD). initE: non-temporal.
// h fp32 + c: block-private cached. hhi/hlo out: wide bypass stores.
// ---------------------------------------------------------------------------
__device__ __forceinline__ void lstm_tile(
    char* smem, int tid, int bx, int by,
    const float* __restrict__ h_in,
    const ushort_t* hhi, const ushort_t* hlo,
    float* __restrict__ h_out,
    ushort_t* hhi_o, ushort_t* hlo_o,
    float* __restrict__ c_st,
    const ushort_t* __restrict__ Whi, const ushort_t* __restrict__ Wlo,
    const float* __restrict__ initE,
    const int* __restrict__ tokens, const int* __restrict__ lengths, int t)
{
    char* As_hi = smem;                  // 8 KB: 64 rows x 8 slots x 16 B
    char* As_lo = smem + 8192;
    float* Gx = (float*)smem;            // epilogue reuse: [4][64][36] fp32

    const int w = tid >> 6;
    const int l = tid & 63;
    const int q = l >> 4;
    const int fr = l & 15;
    const int fbase = bx * 64;
    const int n0 = by * 32;

    const int ar = tid >> 2;
    const int s0 = tid & 3;
    const size_t a_goff = (size_t)(fbase + ar) * HH + s0 * 8;

    const size_t brow0 = ((size_t)(w * HH) + n0 + 0 * 16 + fr) * HH + q * 8;
    const size_t brow1 = ((size_t)(w * HH) + n0 + 1 * 16 + fr) * HH + q * 8;

    floatx4 acc[4][2];
    #pragma unroll
    for (int m = 0; m < 4; ++m)
        #pragma unroll
        for (int n = 0; n < 2; ++n) acc[m][n] = (floatx4)(0.0f);

    // prologue: issue A chunk 0 (bypass, in flight across first sync)
    uintx4 pa_h0, pa_h1, pa_l0, pa_l1;
    bissue4(hhi + a_goff, pa_h0);
    bissue4(hhi + a_goff + 32, pa_h1);
    bissue4(hlo + a_goff, pa_l0);
    bissue4(hlo + a_goff + 32, pa_l1);

    // W chunk 0 (normal cached, double-buffered)
    short8 Bh[2][2][2], Bl[2][2][2];
    #pragma unroll
    for (int kk = 0; kk < 2; ++kk) {
        Bh[0][0][kk] = *(const short8*)(Whi + brow0 + kk * 32);
        Bh[0][1][kk] = *(const short8*)(Whi + brow1 + kk * 32);
        Bl[0][0][kk] = *(const short8*)(Wlo + brow0 + kk * 32);
        Bl[0][1][kk] = *(const short8*)(Wlo + brow1 + kk * 32);
    }

    const int sw0 = (s0 + ar) & 7;
    const int sw1 = ((s0 + 4) + ar) & 7;

    #pragma unroll 2
    for (int kc = 0; kc < 16; ++kc) {
        const int cur = kc & 1, nxt = cur ^ 1;
        __syncthreads();
        bwait4(pa_h0, pa_h1, pa_l0, pa_l1);       // A(kc) has landed
        ((uintx4*)As_hi)[ar * 8 + sw0] = pa_h0;
        ((uintx4*)As_hi)[ar * 8 + sw1] = pa_h1;
        ((uintx4*)As_lo)[ar * 8 + sw0] = pa_l0;
        ((uintx4*)As_lo)[ar * 8 + sw1] = pa_l1;
        __syncthreads();

        if (kc < 15) {
            const int k0 = (kc + 1) * 64;
            bissue4(hhi + a_goff + k0, pa_h0);    // A(kc+1): latency hidden by MFMA
            bissue4(hhi + a_goff + k0 + 32, pa_h1);
            bissue4(hlo + a_goff + k0, pa_l0);
            bissue4(hlo + a_goff + k0 + 32, pa_l1);
            #pragma unroll
            for (int kk = 0; kk < 2; ++kk) {
                Bh[nxt][0][kk] = *(const short8*)(Whi + brow0 + k0 + kk * 32);
                Bh[nxt][1][kk] = *(const short8*)(Whi + brow1 + k0 + kk * 32);
                Bl[nxt][0][kk] = *(const short8*)(Wlo + brow0 + k0 + kk * 32);
                Bl[nxt][1][kk] = *(const short8*)(Wlo + brow1 + k0 + kk * 32);
            }
        }

        #pragma unroll
        for (int m = 0; m < 4; ++m) {
            const int r = m * 16 + fr;
            short8 ah0 = *(const short8*)(As_hi + (r * 8 + ((0 * 4 + q + r) & 7)) * 16);
            short8 ah1 = *(const short8*)(As_hi + (r * 8 + ((1 * 4 + q + r) & 7)) * 16);
            short8 al0 = *(const short8*)(As_lo + (r * 8 + ((0 * 4 + q + r) & 7)) * 16);
            short8 al1 = *(const short8*)(As_lo + (r * 8 + ((1 * 4 + q + r) & 7)) * 16);
            #pragma unroll
            for (int n = 0; n < 2; ++n) {
                acc[m][n] = __builtin_amdgcn_mfma_f32_16x16x32_bf16(ah0, Bh[cur][n][0], acc[m][n], 0, 0, 0);
                acc[m][n] = __builtin_amdgcn_mfma_f32_16x16x32_bf16(al0, Bh[cur][n][0], acc[m][n], 0, 0, 0);
                acc[m][n] = __builtin_amdgcn_mfma_f32_16x16x32_bf16(ah0, Bl[cur][n][0], acc[m][n], 0, 0, 0);
                acc[m][n] = __builtin_amdgcn_mfma_f32_16x16x32_bf16(ah1, Bh[cur][n][1], acc[m][n], 0, 0, 0);
                acc[m][n] = __builtin_amdgcn_mfma_f32_16x16x32_bf16(al1, Bh[cur][n][1], acc[m][n], 0, 0, 0);
                acc[m][n] = __builtin_amdgcn_mfma_f32_16x16x32_bf16(ah1, Bl[cur][n][1], acc[m][n], 0, 0, 0);
            }
        }
    }

    // --- gate exchange (C/D: col = fr, row = q*4 + reg); row stride 36 ---
    __syncthreads();
    #pragma unroll
    for (int m = 0; m < 4; ++m)
        #pragma unroll
        for (int n = 0; n < 2; ++n)
            #pragma unroll
            for (int r = 0; r < 4; ++r)
                Gx[(w * 64 + m * 16 + q * 4 + r) * 36 + n * 16 + fr] = acc[m][n][r];
    __syncthreads();

    // --- fused cell update: thread -> (row rr, 8 cols) = block-private ---
    const int rr = tid >> 2;
    const int c0 = (tid & 3) * 8;
    const int f = fbase + rr;
    const int gc = n0 + c0;
    const size_t gidx = (size_t)f * HH + gc;
    const float* ib = tokens ? (initE + (size_t)tokens[f * LL + t] * 4096)
                             : (initE + (size_t)f * 4096);
    const bool upd = lengths ? (t < lengths[f]) : true;

    float gv[4][8];
    #pragma unroll
    for (int g = 0; g < 4; ++g) {
        float4 x0 = *(const float4*)&Gx[(g * 64 + rr) * 36 + c0];
        float4 x1 = *(const float4*)&Gx[(g * 64 + rr) * 36 + c0 + 4];
        const float4 i0 = ntl4(ib + g * 1024 + gc);       // non-temporal: no L2 alloc
        const float4 i1 = ntl4(ib + g * 1024 + gc + 4);
        gv[g][0] = x0.x + i0.x; gv[g][1] = x0.y + i0.y;
        gv[g][2] = x0.z + i0.z; gv[g][3] = x0.w + i0.w;
        gv[g][4] = x1.x + i1.x; gv[g][5] = x1.y + i1.y;
        gv[g][6] = x1.z + i1.z; gv[g][7] = x1.w + i1.w;
    }
    float4 cv0 = *(const float4*)(c_st + gidx);           // private cached
    float4 cv1 = *(const float4*)(c_st + gidx + 4);
    float4 hv0 = *(const float4*)(h_in + gidx);           // private cached
    float4 hv1 = *(const float4*)(h_in + gidx + 4);
    float cold[8] = {cv0.x, cv0.y, cv0.z, cv0.w, cv1.x, cv1.y, cv1.z, cv1.w};
    float hold[8] = {hv0.x, hv0.y, hv0.z, hv0.w, hv1.x, hv1.y, hv1.z, hv1.w};

    float cw[8], hw[8];
    uintx4 hiv, lov;
    #pragma unroll
    for (int j = 0; j < 8; ++j) {
        float cn = sigm(gv[1][j]) * cold[j] + sigm(gv[0][j]) * tanh_fast(gv[2][j]);
        float hn = sigm(gv[3][j]) * tanh_fast(cn);
        cw[j] = upd ? cn : cold[j];
        hw[j] = upd ? hn : hold[j];
        unsigned short hb, lb;
        split_bf16(hw[j], hb, lb);
        ((ushort_t*)&hiv)[j] = hb;
        ((ushort_t*)&lov)[j] = lb;
    }
    *(float4*)(c_st + gidx)     = make_float4(cw[0], cw[1], cw[2], cw[3]);
    *(float4*)(c_st + gidx + 4) = make_float4(cw[4], cw[5], cw[6], cw[7]);
    *(float4*)(h_out + gidx)     = make_float4(hw[0], hw[1], hw[2], hw[3]);
    *(float4*)(h_out + gidx + 4) = make_float4(hw[4], hw[5], hw[6], hw[7]);
    bstore4(hhi_o + gidx, hiv);                            // wide bypass publish
    bstore4(hlo_o + gidx, lov);
}

// ---------------------------------------------------------------------------
// pooled[b][n] = tanh(max_e(h@Wmp^T) + bmp). h reconstructed from bypass
// bf16 hi+lo (h = hi + lo, err ~2^-17). Tile: programs [bx*16) x cols [by*32).
// ---------------------------------------------------------------------------
__device__ __forceinline__ void pool_tile(char* smem, int tid, int bx, int by,
    const ushort_t* hhi, const ushort_t* hlo,
    const float* __restrict__ Wmp, const float* __restrict__ bmp, float* pooled)
{
    float* As = (float*)smem;               // [32 k][64 rows] stride 65
    float* Bs = (float*)(smem + 16640);     // [32 k][32 cols] stride 33
    const int tm = tid & 15, tn = tid >> 4;
    const int fbase = bx * 64, n0 = by * 32;
    const int ar = tid >> 2;                // row 0..63
    const int ac = (tid & 3) * 8;           // 8 cols per thread per chunk
    const int br = tid >> 3;                // Wmp col 0..31
    const int bk = (tid & 7) * 4;
    const ushort_t* hrow = hhi + (size_t)(fbase + ar) * HH + ac;
    const ushort_t* lrow = hlo + (size_t)(fbase + ar) * HH + ac;
    const float* brow = Wmp + (size_t)(n0 + br) * HH + bk;
    float acc[4][2] = {};
    const int tm4 = tm * 4, tn2 = tn * 2;

    for (int k0 = 0; k0 < HH; k0 += 32) {
        uintx4 vh, vl;
        bload4x2(hrow + k0, lrow + k0, vh, vl);
        float4 bv = ntl4(brow + k0);
        __syncthreads();
        const unsigned int* ph = (const unsigned int*)&vh;
        const unsigned int* pl = (const unsigned int*)&vl;
        #pragma unroll
        for (int j = 0; j < 4; ++j) {
            As[(ac + 2 * j + 0) * 65 + ar] = bf2f(ph[j] & 0xFFFFu) + bf2f(pl[j] & 0xFFFFu);
            As[(ac + 2 * j + 1) * 65 + ar] = bf2f(ph[j] >> 16) + bf2f(pl[j] >> 16);
        }
        Bs[(bk + 0) * 33 + br] = bv.x; Bs[(bk + 1) * 33 + br] = bv.y;
        Bs[(bk + 2) * 33 + br] = bv.z; Bs[(bk + 3) * 33 + br] = bv.w;
        __syncthreads();
        #pragma unroll
        for (int k = 0; k < 32; ++k) {
            float4 a = *(const float4*)&As[k * 65 + tm4];
            float b0 = Bs[k * 33 + tn2], b1 = Bs[k * 33 + tn2 + 1];
            acc[0][0] += a.x * b0; acc[0][1] += a.x * b1;
            acc[1][0] += a.y * b0; acc[1][1] += a.y * b1;
            acc[2][0] += a.z * b0; acc[2][1] += a.z * b1;
            acc[3][0] += a.w * b0; acc[3][1] += a.w * b1;
        }
    }
    float mx0 = fmaxf(fmaxf(acc[0][0], acc[1][0]), fmaxf(acc[2][0], acc[3][0])) + bmp[n0 + tn2];
    float mx1 = fmaxf(fmaxf(acc[0][1], acc[1][1]), fmaxf(acc[2][1], acc[3][1])) + bmp[n0 + tn2 + 1];
    uintx2 ov;
    ov.x = __float_as_uint(tanh_fast(mx0));
    ov.y = __float_as_uint(tanh_fast(mx1));
    bstore2(pooled + (size_t)(bx * 16 + tm) * HH + n0 + tn2, ov);
}

// ---------------------------------------------------------------------------
// logits: out[b][p] = pooled[b] @ Wsm^T + bsm. pooled read via bypass.
// ---------------------------------------------------------------------------
__device__ __forceinline__ void sm_tile(char* smem, int tid, int bx, int by,
    const float* pooled, const float* __restrict__ Wsm,
    const float* __restrict__ bsm, float* __restrict__ outp)
{
    float* As = (float*)smem;               // [64 k][16 rows] stride 17
    float* Bs = (float*)(smem + 4352);      // [64 k][32 cols] stride 33
    const int tm = tid & 15, tn = tid >> 4;
    const int n0 = by * 32;
    const int ara = tid >> 4;               // row 0..15
    const int ak4 = (tid & 15) * 4;         // 4 cols per thread per chunk
    const int brb = tid >> 3;               // col 0..31
    const int bkb = (tid & 7) * 8;
    const float* arow = pooled + (size_t)(bx * 16 + ara) * HH + ak4;
    const float* brow = Wsm + (size_t)(n0 + brb) * HH + bkb;
    float a0 = 0.f, a1 = 0.f;
    const int tn2 = tn * 2;

    for (int k0 = 0; k0 < HH; k0 += 64) {
        uintx4 av = bload4(arow + k0);
        float4 bv0 = ntl4(brow + k0);
        float4 bv1 = ntl4(brow + k0 + 4);
        __syncthreads();
        const float* af = (const float*)&av;
        #pragma unroll
        for (int j = 0; j < 4; ++j) As[(ak4 + j) * 17 + ara] = af[j];
        Bs[(bkb + 0) * 33 + brb] = bv0.x; Bs[(bkb + 1) * 33 + brb] = bv0.y;
        Bs[(bkb + 2) * 33 + brb] = bv0.z; Bs[(bkb + 3) * 33 + brb] = bv0.w;
        Bs[(bkb + 4) * 33 + brb] = bv1.x; Bs[(bkb + 5) * 33 + brb] = bv1.y;
        Bs[(bkb + 6) * 33 + brb] = bv1.z; Bs[(bkb + 7) * 33 + brb] = bv1.w;
        __syncthreads();
        #pragma unroll
        for (int k = 0; k < 64; ++k) {
            float a = As[k * 17 + tm];
            a0 += a * Bs[k * 33 + tn2];
            a1 += a * Bs[k * 33 + tn2 + 1];
        }
    }
    float2 o; o.x = a0 + bsm[n0 + tn2]; o.y = a1 + bsm[n0 + tn2 + 1];
    *(float2*)(outp + (size_t)(bx * 16 + tm) * PP + n0 + tn2) = o;
}

// ---------------------------------------------------------------------------
// Persistent encoder: both LSTM phases (256 steps) in ONE launch.
// ---------------------------------------------------------------------------
__global__ __launch_bounds__(256, 2) void persist_enc(
    const int* __restrict__ tokens_in, const int* __restrict__ lengths_in,
    const int* __restrict__ tokens_out, const int* __restrict__ lengths_out,
    const ushort_t* __restrict__ Whi_in, const ushort_t* __restrict__ Wlo_in,
    const ushort_t* __restrict__ Whi_out, const ushort_t* __restrict__ Wlo_out,
    const float* __restrict__ embW_in, const float* __restrict__ embW_out,
    float* h_a, ushort_t* hhi_a, ushort_t* hlo_a,
    float* h_b, ushort_t* hhi_b, ushort_t* hlo_b,
    float* c_st, unsigned int* barcnt)
{
    __shared__ __align__(16) char smem[36864];
    const int tid = threadIdx.x;
    const int id = blockIdx.x;
    const int by = (id & 7) + 8 * ((id >> 3) & 3);
    const int bx = id >> 5;
    unsigned int* cnt = barcnt + bx * 32;
    unsigned int barv = 0;

    float* hc = h_a;  ushort_t* hic = hhi_a;  ushort_t* lcc = hlo_a;
    float* hn = h_b;  ushort_t* hin = hhi_b;  ushort_t* lnn = hlo_b;

    for (int ph = 0; ph < 2; ++ph) {
        const int* tok = ph ? tokens_out : tokens_in;
        const int* len = ph ? lengths_out : lengths_in;
        const ushort_t* Wh = ph ? Whi_out : Whi_in;
        const ushort_t* Wl = ph ? Wlo_out : Wlo_in;
        const float* iE = ph ? embW_out : embW_in;
        for (int t = 0; t < 128; ++t) {
            lstm_tile(smem, tid, bx, by, hc, hic, lcc, hn, hin, lnn, c_st,
                      Wh, Wl, iE, tok, len, t);
            { float* tf = hc; hc = hn; hn = tf; }
            { ushort_t* th = hic; hic = hin; hin = th; }
            { ushort_t* tl = lcc; lcc = lnn; lnn = tl; }
            ++barv;
            group_bar(cnt, 32u * barv);
        }
    }
}

// ---------------------------------------------------------------------------
// Persistent decoder: 16 x (lstm -> pool -> softmax) in ONE launch.
// ---------------------------------------------------------------------------
__global__ __launch_bounds__(256, 2) void persist_dec(
    const ushort_t* __restrict__ Whi_p, const ushort_t* __restrict__ Wlo_p,
    const float* __restrict__ u_p,
    const float* __restrict__ W_mp, const float* __restrict__ b_mp,
    const float* __restrict__ W_sm, const float* __restrict__ b_sm,
    float* h_a, ushort_t* hhi_a, ushort_t* hlo_a,
    float* h_b, ushort_t* hhi_b, ushort_t* hlo_b,
    float* c_st, float* pooled, float* out, unsigned int* barcnt)
{
    __shared__ __align__(16) char smem[36864];
    const int tid = threadIdx.x;
    const int id = blockIdx.x;
    const int by = (id & 7) + 8 * ((id >> 3) & 3);
    const int bx = id >> 5;
    unsigned int* cnt = barcnt + bx * 32;
    unsigned int barv = 0;

    float* hc = h_a;  ushort_t* hic = hhi_a;  ushort_t* lcc = hlo_a;
    float* hn = h_b;  ushort_t* hin = hhi_b;  ushort_t* lnn = hlo_b;

    for (int t = 0; t < 16; ++t) {
        lstm_tile(smem, tid, bx, by, hc, hic, lcc, hn, hin, lnn, c_st,
                  Whi_p, Wlo_p, u_p, nullptr, nullptr, t);
        { float* tf = hc; hc = hn; hn = tf; }
        { ushort_t* th = hic; hic = hin; hin = th; }
        { ushort_t* tl = lcc; lcc = lnn; lnn = tl; }
        ++barv; group_bar(cnt, 32u * barv);

        pool_tile(smem, tid, bx, by, hic, lcc, W_mp, b_mp, pooled);
        ++barv; group_bar(cnt, 32u * barv);

        sm_tile(smem, tid, bx, by, pooled, W_sm, b_sm, out + (size_t)t * (BB * PP));
        ++barv; group_bar(cnt, 32u * barv);
    }
}

// ---------------------------------------------------------------------------
// Generic fp32 C[M][N] = A[M][K] @ W[N][K]^T + bias[N]; grid (M/32, N/64).
// ---------------------------------------------------------------------------
__global__ __launch_bounds__(256) void gemm_bias(
    const float* __restrict__ A, const float* __restrict__ W,
    const float* __restrict__ bias, float* __restrict__ C,
    int N, int K)
{
    __shared__ __align__(16) float As[16][32];
    __shared__ __align__(16) float Bs[16][64];
    const int tid = threadIdx.x;
    const int tm = tid & 7;
    const int tn = tid >> 3;
    const int m0 = blockIdx.x * 32, n0 = blockIdx.y * 64;
    const int am = tid >> 3;
    const int ak = (tid & 7) * 2;
    const int br = tid >> 2;
    const int bk = (tid & 3) * 4;
    const float* arow = A + (size_t)(m0 + am) * K;
    const float* brow = W + (size_t)(n0 + br) * K;
    float acc[4][2] = {};
    const int tm4 = tm * 4, tn2 = tn * 2;

    for (int k0 = 0; k0 < K; k0 += 16) {
        __syncthreads();
        float2 av = *(const float2*)(arow + k0 + ak);
        float4 bv = *(const float4*)(brow + k0 + bk);
        As[ak][am] = av.x; As[ak + 1][am] = av.y;
        Bs[bk][br] = bv.x; Bs[bk + 1][br] = bv.y;
        Bs[bk + 2][br] = bv.z; Bs[bk + 3][br] = bv.w;
        __syncthreads();
        #pragma unroll
        for (int k = 0; k < 16; ++k) {
            float4 a = *(const float4*)&As[k][tm4];
            float2 b = *(const float2*)&Bs[k][tn2];
            acc[0][0] += a.x * b.x; acc[0][1] += a.x * b.y;
            acc[1][0] += a.y * b.x; acc[1][1] += a.y * b.y;
            acc[2][0] += a.z * b.x; acc[2][1] += a.z * b.y;
            acc[3][0] += a.w * b.x; acc[3][1] += a.w * b.y;
        }
    }
    float b0 = bias[n0 + tn2], b1 = bias[n0 + tn2 + 1];
    #pragma unroll
    for (int mi = 0; mi < 4; ++mi) {
        float2 o;
        o.x = acc[mi][0] + b0;
        o.y = acc[mi][1] + b1;
        *(float2*)(C + (size_t)(m0 + tm4 + mi) * N + n0 + tn2) = o;
    }
}

extern "C" void kernel_launch(void* const* d_in, const int* in_sizes, int n_in,
                              void* d_out, int out_size, void* d_ws, size_t ws_size,
                              hipStream_t stream)
{
    const int*   tokens_in   = (const int*)d_in[0];
    const int*   lengths_in  = (const int*)d_in[1];
    const int*   tokens_out  = (const int*)d_in[2];
    const int*   lengths_out = (const int*)d_in[3];
    const float* embedding   = (const float*)d_in[4];
    const float* W_ih_in     = (const float*)d_in[5];
    const float* W_hh_in     = (const float*)d_in[6];
    const float* b_in        = (const float*)d_in[7];
    const float* W_ih_out    = (const float*)d_in[8];
    const float* W_hh_out    = (const float*)d_in[9];
    const float* b_out       = (const float*)d_in[10];
    const float* W_ih_p      = (const float*)d_in[11];
    const float* W_hh_p      = (const float*)d_in[12];
    const float* b_p         = (const float*)d_in[13];
    const float* W_mp        = (const float*)d_in[14];
    const float* b_mp        = (const float*)d_in[15];
    const float* W_sm        = (const float*)d_in[16];
    const float* b_sm        = (const float*)d_in[17];
    float* out = (float*)d_out;

    float* ws = (float*)d_ws;
    float* h_a      = ws;                  // 524288
    float* h_b      = ws + 524288;
    float* c_st     = ws + 1048576;
    float* embW_in  = ws + 1572864;
    float* embW_out = ws + 2097152;
    float* u_p      = ws + 2621440;        // 2097152
    float* pooled   = ws + 4718592;        // 131072
    ushort_t* hhi_a = (ushort_t*)(ws + 4849664);
    ushort_t* hlo_a = (ushort_t*)(ws + 5111808);
    ushort_t* hhi_b = (ushort_t*)(ws + 5373952);
    ushort_t* hlo_b = (ushort_t*)(ws + 5636096);
    ushort_t* Whi_in  = (ushort_t*)(ws + 5898240);
    ushort_t* Wlo_in  = (ushort_t*)(ws + 7995392);
    ushort_t* Whi_out = (ushort_t*)(ws + 10092544);
    ushort_t* Wlo_out = (ushort_t*)(ws + 12189696);
    ushort_t* Whi_p   = (ushort_t*)(ws + 14286848);
    ushort_t* Wlo_p   = (ushort_t*)(ws + 16384000);
    unsigned int* barcnt = (unsigned int*)(ws + 18481152); // 512 uints

    fillz<<<2048, 256, 0, stream>>>(h_a, 524288);
    fillz<<<2048, 256, 0, stream>>>(c_st, 524288);
    fillz<<<2048, 256, 0, stream>>>(ws + 4849664, 524288);  // hhi_a+hlo_a
    fillz<<<2, 256, 0, stream>>>((float*)barcnt, 512);

    split_w<<<16384, 256, 0, stream>>>(W_hh_in,  Whi_in,  Wlo_in,  4194304);
    split_w<<<16384, 256, 0, stream>>>(W_hh_out, Whi_out, Wlo_out, 4194304);
    split_w<<<16384, 256, 0, stream>>>(W_hh_p,   Whi_p,   Wlo_p,   4194304);

    gemm_bias<<<dim3(4, 64), 256, 0, stream>>>(embedding, W_ih_in, b_in, embW_in, 4096, 128);
    gemm_bias<<<dim3(4, 64), 256, 0, stream>>>(embedding, W_ih_out, b_out, embW_out, 4096, 128);

    persist_enc<<<256, 256, 0, stream>>>(
        tokens_in, lengths_in, tokens_out, lengths_out,
        Whi_in, Wlo_in, Whi_out, Wlo_out, embW_in, embW_out,
        h_a, hhi_a, hlo_a, h_b, hhi_b, hlo_b, c_st, barcnt);

    gemm_bias<<<dim3(16, 64), 256, 0, stream>>>(h_a, W_ih_p, b_p, u_p, 4096, 1024);

    persist_dec<<<256, 256, 0, stream>>>(
        Whi_p, Wlo_p, u_p, W_mp, b_mp, W_sm, b_sm,
        h_a, hhi_a, hlo_a, h_b, hhi_b, hlo_b, c_st, pooled, out, barcnt + 256);
}